// Round 8
// baseline (272.557 us; speedup 1.0000x reference)
//
#include <hip/hip_runtime.h>
#include <cstddef>

#define D   64
#define L   128
#define NT  512            // 8 waves per block
#define ROWS 16            // one M=16 MFMA tile per block
#define XSS 132            // padded floats (mult of 4 keeps float4 alignment)
#define HBS 72             // shorts
#define GS  17             // gbuf row-stride (floats): odd -> conflict-free reads
#define NBLK 512           // 8192 / 16
#define LOG2E 1.4426950408889634f

typedef __attribute__((ext_vector_type(8))) short short8;
typedef __attribute__((ext_vector_type(4))) float floatx4;

__device__ __forceinline__ float fast_rcp(float x) {
#if defined(__has_builtin)
#if __has_builtin(__builtin_amdgcn_rcpf)
  return __builtin_amdgcn_rcpf(x);
#else
  return 1.0f / x;
#endif
#else
  return 1.0f / x;
#endif
}
__device__ __forceinline__ float ex2(float x) {
#if defined(__has_builtin)
#if __has_builtin(__builtin_amdgcn_exp2f)
  return __builtin_amdgcn_exp2f(x);
#else
  return __builtin_exp2f(x);
#endif
#else
  return __builtin_exp2f(x);
#endif
}
__device__ __forceinline__ float sig_plain(float x) {
  return fast_rcp(1.0f + ex2(-LOG2E * x));
}
__device__ __forceinline__ float tanh2(float G) {   // tanh(x), G = -2log2e*x
  return fmaf(2.0f, fast_rcp(1.0f + ex2(G)), -1.0f);
}
__device__ __forceinline__ unsigned short f2bf_rtne(float f) {
  unsigned int u = __float_as_uint(f);
  u += 0x7fffu + ((u >> 16) & 1u);
  return (unsigned short)(u >> 16);
}
__device__ __forceinline__ float bf2f(unsigned short s) {
  return __uint_as_float(((unsigned int)s) << 16);
}

// Persistent 16-row LSTM scan, 8-wave blocks for 4 waves/SIMD TLP.
// Wave w = (wg=w>>2, wq=w&3): MFMA phase computes gate-pair wg ({i,f} or
// {g,o}) for d-tile wq (8 MFMAs, 2-term split: A=rtne-bf16(h), B=W hi+lo).
// Gates round-trip through stride-17 LDS (conflict-free); elementwise is
// re-partitioned 2 cells/lane across ALL 8 waves (lane owns (row=2w+lane/32,
// d=lane%32 and d+32); c-state register-resident per lane for all 128 steps).
// Two barriers/step. Gates prescaled by -log2e (-2log2e for g): merged
// algebra = 5 exp2 + 2 rcp per cell.
__global__ __launch_bounds__(NT, 4)
void lstm_main(const float* __restrict__ x,
               const float* __restrict__ W_num,
               const float* __restrict__ b_num,
               const float* __restrict__ W_ih,
               const float* __restrict__ W_hh,
               const float* __restrict__ b_ih,
               const float* __restrict__ b_hh,
               const float* __restrict__ W_aout,
               const float* __restrict__ b_aout,
               const float* __restrict__ W_fh,
               const float* __restrict__ b_fh,
               const float* __restrict__ W_iouh,
               const float* __restrict__ b_iouh,
               const float* __restrict__ W_oout,
               const float* __restrict__ b_oout,
               float* __restrict__ acc_out,   // [0..63]=fc, [64..127]=hs, [128]=ticket
               float* __restrict__ out)
{
  __shared__ __align__(16) float xs[ROWS * XSS];       // 8.25 KB (x; later h/h_hat)
  __shared__ __align__(16) float gbuf[4 * 64 * GS];    // 17 KB gate exchange
  __shared__ __align__(16) short hb[2][ROWS * HBS];    // 4.5 KB double-buffered bf16 h
  __shared__ float sacc[2 * D];
  __shared__ float hobj[D];
  __shared__ int   is_last;

  const int tid  = threadIdx.x;
  const int w    = tid >> 6;       // 0..7
  const int wq   = w & 3;          // d-tile
  const int wg   = w >> 2;         // gate-pair: 0 -> {i,f}, 1 -> {g,o}
  const int lane = tid & 63;
  const int quad = lane >> 4;
  const int c16  = lane & 15;
  const int k0   = blockIdx.x * ROWS;
  const int dcol = wq * 16 + c16;          // MFMA-phase d
  const int erow = 2 * w + (lane >> 5);    // elementwise-phase row (0..15)
  const int dd0  = lane & 31;              // elementwise-phase d's
  const int dd1  = dd0 + 32;

  // ---- stage x tile (16 rows x 128), coalesced; zero hb[0] and sacc ----
  for (int i = tid; i < ROWS * (L / 4); i += NT) {
    int r = i >> 5, c4 = i & 31;
    float4 v = ((const float4*)(x + (size_t)(k0 + r) * L))[c4];
    float* dst = &xs[r * XSS + c4 * 4];
    dst[0] = v.x; dst[1] = v.y; dst[2] = v.z; dst[3] = v.w;
  }
  for (int i = tid; i < ROWS * HBS; i += NT) hb[0][i] = 0;
  if (tid < 2 * D) sacc[tid] = 0.0f;

  // per-gate exp2 prescale (g-gate feeds tanh -> -2log2e)
  const float gscale[4] = {-LOG2E, -LOG2E, -2.0f * LOG2E, -LOG2E};

  // ---- rank-1 x-projection constants for this wave's 2 gates ----
  float An[2], Bc[2];
#pragma unroll
  for (int gl = 0; gl < 2; ++gl) {
    int g = 2 * wg + gl;
    int j = g * 64 + dcol;
    const float4* wr = (const float4*)(W_ih + (size_t)j * (2 * D));
    float a = 0.0f, b = b_ih[j] + b_hh[j];
#pragma unroll
    for (int e4 = 0; e4 < 16; ++e4) {
      float4 wv = wr[e4];
      float4 wn = ((const float4*)W_num)[e4];
      float4 bn = ((const float4*)b_num)[e4];
      a = fmaf(wn.x, wv.x, a); a = fmaf(wn.y, wv.y, a);
      a = fmaf(wn.z, wv.z, a); a = fmaf(wn.w, wv.w, a);
      b = fmaf(bn.x, wv.x, b); b = fmaf(bn.y, wv.y, b);
      b = fmaf(bn.z, wv.z, b); b = fmaf(bn.w, wv.w, b);
    }
    An[gl] = a * gscale[g]; Bc[gl] = b * gscale[g];
  }

  // ---- W_hh B-fragments for this wave's 2 gates (hi+lo exact) ----
  short8 Bhi[2][2], Blo[2][2];   // [gl][kk]
#pragma unroll
  for (int gl = 0; gl < 2; ++gl) {
    int g = 2 * wg + gl;
#pragma unroll
    for (int kk = 0; kk < 2; ++kk) {
      const float4* wp = (const float4*)(W_hh + (size_t)(g * 64 + dcol) * D
                                         + kk * 32 + quad * 8);
      float wv[8];
      float4 w0 = wp[0], w1 = wp[1];
      wv[0]=w0.x; wv[1]=w0.y; wv[2]=w0.z; wv[3]=w0.w;
      wv[4]=w1.x; wv[5]=w1.y; wv[6]=w1.z; wv[7]=w1.w;
      short8 hi8, lo8;
#pragma unroll
      for (int j = 0; j < 8; ++j) {
        float v = wv[j] * gscale[g];
        unsigned short h = f2bf_rtne(v);
        hi8[j] = (short)h;
        lo8[j] = (short)f2bf_rtne(v - bf2f(h));
      }
      Bhi[gl][kk] = hi8; Blo[gl][kk] = lo8;
    }
  }

  float c0 = 0.0f, c1 = 0.0f;     // cell state for (erow,dd0),(erow,dd1)
  float h0 = 0.0f, h1 = 0.0f;
  __syncthreads();

  int p = 0;
  for (int t4 = 0; t4 < L; t4 += 4) {
    float4 xq[4];
#pragma unroll
    for (int r = 0; r < 4; ++r)
      xq[r] = *(const float4*)&xs[(quad * 4 + r) * XSS + t4];
#pragma unroll
    for (int u = 0; u < 4; ++u) {
      // --- MFMA phase: this wave's 2 gates for d-tile wq ---
      short8 ahi[2];
#pragma unroll
      for (int kk = 0; kk < 2; ++kk)
        ahi[kk] = *(const short8*)&hb[p][c16 * HBS + kk * 32 + quad * 8];
      float xv[4] = {xq[0][u], xq[1][u], xq[2][u], xq[3][u]};
      floatx4 acc[2];
#pragma unroll
      for (int gl = 0; gl < 2; ++gl)
        acc[gl] = (floatx4){fmaf(An[gl], xv[0], Bc[gl]), fmaf(An[gl], xv[1], Bc[gl]),
                            fmaf(An[gl], xv[2], Bc[gl]), fmaf(An[gl], xv[3], Bc[gl])};
#pragma unroll
      for (int kk = 0; kk < 2; ++kk) {
#pragma unroll
        for (int gl = 0; gl < 2; ++gl) {
          acc[gl] = __builtin_amdgcn_mfma_f32_16x16x32_bf16(ahi[kk], Bhi[gl][kk], acc[gl], 0, 0, 0);
          acc[gl] = __builtin_amdgcn_mfma_f32_16x16x32_bf16(ahi[kk], Blo[gl][kk], acc[gl], 0, 0, 0);
        }
      }
      // scatter gates: gbuf[(g*64 + d)*GS + row], banks ~2-way (free)
#pragma unroll
      for (int gl = 0; gl < 2; ++gl) {
        int gbase = ((2 * wg + gl) * 64 + dcol) * GS + quad * 4;
#pragma unroll
        for (int r = 0; r < 4; ++r) gbuf[gbase + r] = acc[gl][r];
      }
      __syncthreads();
      // --- elementwise phase: 2 cells/lane across all 8 waves ---
      {
        float Gi0 = gbuf[(0 * 64 + dd0) * GS + erow];
        float Gf0 = gbuf[(1 * 64 + dd0) * GS + erow];
        float Gg0 = gbuf[(2 * 64 + dd0) * GS + erow];
        float Go0 = gbuf[(3 * 64 + dd0) * GS + erow];
        float Gi1 = gbuf[(0 * 64 + dd1) * GS + erow];
        float Gf1 = gbuf[(1 * 64 + dd1) * GS + erow];
        float Gg1 = gbuf[(2 * 64 + dd1) * GS + erow];
        float Go1 = gbuf[(3 * 64 + dd1) * GS + erow];
        float Ei0 = ex2(Gi0), Ef0 = ex2(Gf0), Eg0 = ex2(Gg0), Eo0 = ex2(Go0);
        float Ei1 = ex2(Gi1), Ef1 = ex2(Gf1), Eg1 = ex2(Gg1), Eo1 = ex2(Go1);
        float pf0 = 1.0f + Ef0, pi0 = 1.0f + Ei0, pg0 = 1.0f + Eg0, mg0 = 1.0f - Eg0;
        float pf1 = 1.0f + Ef1, pi1 = 1.0f + Ei1, pg1 = 1.0f + Eg1, mg1 = 1.0f - Eg1;
        float pig0 = pi0 * pg0, pig1 = pi1 * pg1;
        float nc0 = fmaf(c0, pig0, mg0 * pf0);
        float nc1 = fmaf(c1, pig1, mg1 * pf1);
        c0 = nc0 * fast_rcp(pf0 * pig0);
        c1 = nc1 * fast_rcp(pf1 * pig1);
        float Ec0 = ex2(-2.0f * LOG2E * c0);
        float Ec1 = ex2(-2.0f * LOG2E * c1);
        h0 = (1.0f - Ec0) * fast_rcp((1.0f + Eo0) * (1.0f + Ec0));
        h1 = (1.0f - Ec1) * fast_rcp((1.0f + Eo1) * (1.0f + Ec1));
        short* hw = &hb[p ^ 1][erow * HBS];
        hw[dd0] = (short)f2bf_rtne(h0);
        hw[dd1] = (short)f2bf_rtne(h1);
      }
      __syncthreads();
      p ^= 1;
    }
  }

  // ---- tail: h_hat = h@W_aout.T+b ; f = h_hat@W_fh.T+b ; partial sums ----
  xs[erow * XSS + dd0] = h0;
  xs[erow * XSS + dd1] = h1;
  __syncthreads();

  float hh0 = b_aout[dd0], hh1 = b_aout[dd1];
  {
    const float4* wa0 = (const float4*)(W_aout + (size_t)dd0 * D);
    const float4* wa1 = (const float4*)(W_aout + (size_t)dd1 * D);
    const float* hp = &xs[erow * XSS];
#pragma unroll
    for (int e4 = 0; e4 < 16; ++e4) {
      float4 v0 = wa0[e4], v1 = wa1[e4];
      float p0 = hp[e4*4+0], p1 = hp[e4*4+1], p2 = hp[e4*4+2], p3 = hp[e4*4+3];
      hh0 = fmaf(v0.x, p0, hh0); hh0 = fmaf(v0.y, p1, hh0);
      hh0 = fmaf(v0.z, p2, hh0); hh0 = fmaf(v0.w, p3, hh0);
      hh1 = fmaf(v1.x, p0, hh1); hh1 = fmaf(v1.y, p1, hh1);
      hh1 = fmaf(v1.z, p2, hh1); hh1 = fmaf(v1.w, p3, hh1);
    }
  }
  // h_hat region (64..127) disjoint from h region (0..63): no barrier needed
  xs[erow * XSS + 64 + dd0] = hh0;
  xs[erow * XSS + 64 + dd1] = hh1;
  __syncthreads();

  float f0 = b_fh[dd0], f1 = b_fh[dd1];
  {
    const float4* wf0 = (const float4*)(W_fh + (size_t)dd0 * D);
    const float4* wf1 = (const float4*)(W_fh + (size_t)dd1 * D);
    const float* hp = &xs[erow * XSS + 64];
#pragma unroll
    for (int e4 = 0; e4 < 16; ++e4) {
      float4 v0 = wf0[e4], v1 = wf1[e4];
      float p0 = hp[e4*4+0], p1 = hp[e4*4+1], p2 = hp[e4*4+2], p3 = hp[e4*4+3];
      f0 = fmaf(v0.x, p0, f0); f0 = fmaf(v0.y, p1, f0);
      f0 = fmaf(v0.z, p2, f0); f0 = fmaf(v0.w, p3, f0);
      f1 = fmaf(v1.x, p0, f1); f1 = fmaf(v1.y, p1, f1);
      f1 = fmaf(v1.z, p2, f1); f1 = fmaf(v1.w, p3, f1);
    }
  }
  float pfc0 = sig_plain(f0) * c0, pfc1 = sig_plain(f1) * c1;
  float phs0 = hh0, phs1 = hh1;
  // combine the two rows sharing (dd0,dd1) within this wave
  pfc0 += __shfl_xor(pfc0, 32); pfc1 += __shfl_xor(pfc1, 32);
  phs0 += __shfl_xor(phs0, 32); phs1 += __shfl_xor(phs1, 32);
  if (lane < 32) {
    atomicAdd(&sacc[dd0], pfc0);
    atomicAdd(&sacc[dd1], pfc1);
    atomicAdd(&sacc[D + dd0], phs0);
    atomicAdd(&sacc[D + dd1], phs1);
  }
  __syncthreads();
  if (tid < 2 * D) atomicAdd(acc_out + tid, sacc[tid]);
  __syncthreads();

  // ---- last-block finish ----
  __threadfence();
  if (tid == 0) {
    unsigned int prev = __hip_atomic_fetch_add((unsigned int*)(acc_out + 2 * D), 1u,
                                               __ATOMIC_ACQ_REL, __HIP_MEMORY_SCOPE_AGENT);
    is_last = (prev == NBLK - 1) ? 1 : 0;
  }
  __syncthreads();
  if (!is_last) return;
  __threadfence();
  if (tid < 2 * D)
    sacc[tid] = __hip_atomic_load(acc_out + tid, __ATOMIC_RELAXED, __HIP_MEMORY_SCOPE_AGENT);
  __syncthreads();
  if (tid < D) {
    const int d = tid;
    float vi = b_iouh[d], vo = b_iouh[D + d], vu = b_iouh[2 * D + d];
    for (int e = 0; e < D; ++e) {
      float hs = sacc[D + e];
      vi = fmaf(W_iouh[(size_t)d * D + e],           hs, vi);
      vo = fmaf(W_iouh[(size_t)(D + d) * D + e],     hs, vo);
      vu = fmaf(W_iouh[(size_t)(2 * D + d) * D + e], hs, vu);
    }
    float c_obj = sig_plain(vi) * tanh2(-2.0f * LOG2E * vu) + sacc[d];
    float h_obj = sig_plain(vo) * tanh2(-2.0f * LOG2E * c_obj);
    hobj[d] = h_obj;
    out[D + d] = c_obj;
  }
  __syncthreads();
  if (tid < D) {
    const int d = tid;
    float hh = b_oout[d];
    for (int e = 0; e < D; ++e) hh = fmaf(W_oout[(size_t)d * D + e], hobj[e], hh);
    out[d] = hh;
  }
}

extern "C" void kernel_launch(void* const* d_in, const int* in_sizes, int n_in,
                              void* d_out, int out_size, void* d_ws, size_t ws_size,
                              hipStream_t stream) {
  const float* x      = (const float*)d_in[0];
  const float* W_num  = (const float*)d_in[1];
  const float* b_num  = (const float*)d_in[2];
  const float* W_ih   = (const float*)d_in[3];
  const float* W_hh   = (const float*)d_in[4];
  const float* b_ih   = (const float*)d_in[5];
  const float* b_hh   = (const float*)d_in[6];
  const float* W_aout = (const float*)d_in[7];
  const float* b_aout = (const float*)d_in[8];
  const float* W_fh   = (const float*)d_in[9];
  const float* b_fh   = (const float*)d_in[10];
  const float* W_iouh = (const float*)d_in[11];
  const float* b_iouh = (const float*)d_in[12];
  const float* W_oout = (const float*)d_in[13];
  const float* b_oout = (const float*)d_in[14];
  float* acc = (float*)d_ws;
  float* out = (float*)d_out;

  hipMemsetAsync(d_ws, 0, (2 * D + 1) * sizeof(float), stream);
  lstm_main<<<NBLK, NT, 0, stream>>>(x, W_num, b_num, W_ih, W_hh, b_ih, b_hh,
                                     W_aout, b_aout, W_fh, b_fh,
                                     W_iouh, b_iouh, W_oout, b_oout, acc, out);
}

// Round 9
// 270.971 us; speedup vs baseline: 1.0059x; 1.0059x over previous
//
#include <hip/hip_runtime.h>
#include <cstddef>

#define D   64
#define L   128
#define NT  256            // 4 waves per block
#define ROWS 8             // rows per block (half-filled M=16 MFMA tile)
#define XSS 132            // padded floats (mult of 4 keeps float4 alignment)
#define HBS 72             // shorts
#define NBLK 1024          // 8192 / 8
#define LOG2E 1.4426950408889634f

typedef __attribute__((ext_vector_type(8))) short short8;
typedef __attribute__((ext_vector_type(4))) float floatx4;

__device__ __forceinline__ float fast_rcp(float x) {
#if defined(__has_builtin)
#if __has_builtin(__builtin_amdgcn_rcpf)
  return __builtin_amdgcn_rcpf(x);
#else
  return 1.0f / x;
#endif
#else
  return 1.0f / x;
#endif
}
__device__ __forceinline__ float ex2(float x) {
#if defined(__has_builtin)
#if __has_builtin(__builtin_amdgcn_exp2f)
  return __builtin_amdgcn_exp2f(x);
#else
  return __builtin_exp2f(x);
#endif
#else
  return __builtin_exp2f(x);
#endif
}
__device__ __forceinline__ float sig_plain(float x) {
  return fast_rcp(1.0f + ex2(-LOG2E * x));
}
__device__ __forceinline__ float tanh2(float G) {   // tanh(x), G = -2log2e*x
  return fmaf(2.0f, fast_rcp(1.0f + ex2(G)), -1.0f);
}
__device__ __forceinline__ unsigned short f2bf_rtne(float f) {
  unsigned int u = __float_as_uint(f);
  u += 0x7fffu + ((u >> 16) & 1u);
  return (unsigned short)(u >> 16);
}
__device__ __forceinline__ float bf2f(unsigned short s) {
  return __uint_as_float(((unsigned int)s) << 16);
}

// Persistent 8-row LSTM scan, R7 structure with halved rows/block:
// 1024 blocks x 4 waves = 4 waves/SIMD TLP (R7 had 2). The M=16 MFMA tile
// is half-filled: real row q*2+r lives in tile-row q*4+r (r=0,1); tile-rows
// ==2,3 (mod 4) are permanently zero in hb, so every quad owns 2 valid rows
// and the elementwise runs with all 64 lanes active at half the per-wave
// issue cost. Chip-wide MFMA doubles (pipe is only ~19% busy - cheap trade).
// Wave w owns d in [16w,16w+16) for all 4 gates -> gates stay in registers,
// one barrier/step. 2-term MFMA split: A=rtne-bf16(h), B=W_hh hi+lo exact.
// Gates prescaled by -log2e (-2log2e for g): 5 exp2 + 2 rcp per cell.
__global__ __launch_bounds__(NT, 4)
void lstm_main(const float* __restrict__ x,
               const float* __restrict__ W_num,
               const float* __restrict__ b_num,
               const float* __restrict__ W_ih,
               const float* __restrict__ W_hh,
               const float* __restrict__ b_ih,
               const float* __restrict__ b_hh,
               const float* __restrict__ W_aout,
               const float* __restrict__ b_aout,
               const float* __restrict__ W_fh,
               const float* __restrict__ b_fh,
               const float* __restrict__ W_iouh,
               const float* __restrict__ b_iouh,
               const float* __restrict__ W_oout,
               const float* __restrict__ b_oout,
               float* __restrict__ acc_out,   // [0..63]=fc, [64..127]=hs, [128]=ticket
               float* __restrict__ out)
{
  __shared__ __align__(16) float xs[ROWS * XSS];       // 4.1 KB (x; later h/h_hat)
  __shared__ __align__(16) short hb[2][16 * HBS];      // 4.5 KB double-buffered bf16 h
  __shared__ float sacc[2 * D];
  __shared__ float hobj[D];
  __shared__ int   is_last;

  const int tid  = threadIdx.x;
  const int w    = tid >> 6;
  const int lane = tid & 63;
  const int quad = lane >> 4;
  const int c16  = lane & 15;
  const int k0   = blockIdx.x * ROWS;
  const int dcol = w * 16 + c16;

  // ---- stage x tile (8 rows x 128), coalesced ----
  for (int i = tid; i < ROWS * (L / 4); i += NT) {
    int r = i >> 5, c4 = i & 31;
    float4 v = ((const float4*)(x + (size_t)(k0 + r) * L))[c4];
    float* dst = &xs[r * XSS + c4 * 4];
    dst[0] = v.x; dst[1] = v.y; dst[2] = v.z; dst[3] = v.w;
  }
  // zero BOTH hb buffers: tile-rows ==2,3 (mod 4) must stay zero forever
  for (int i = tid; i < 2 * 16 * HBS; i += NT) (&hb[0][0])[i] = 0;

  // per-gate exp2 prescale (g-gate feeds tanh -> -2log2e)
  const float gscale[4] = {-LOG2E, -LOG2E, -2.0f * LOG2E, -LOG2E};

  // ---- rank-1 x-projection constants (prescaled), float4 loads ----
  float An[4], Bc[4];
#pragma unroll
  for (int g = 0; g < 4; ++g) {
    int j = g * 64 + dcol;
    const float4* wr = (const float4*)(W_ih + (size_t)j * (2 * D));
    float a = 0.0f, b = b_ih[j] + b_hh[j];
#pragma unroll
    for (int e4 = 0; e4 < 16; ++e4) {
      float4 wv = wr[e4];
      float4 wn = ((const float4*)W_num)[e4];
      float4 bn = ((const float4*)b_num)[e4];
      a = fmaf(wn.x, wv.x, a); a = fmaf(wn.y, wv.y, a);
      a = fmaf(wn.z, wv.z, a); a = fmaf(wn.w, wv.w, a);
      b = fmaf(bn.x, wv.x, b); b = fmaf(bn.y, wv.y, b);
      b = fmaf(bn.z, wv.z, b); b = fmaf(bn.w, wv.w, b);
    }
    An[g] = a * gscale[g]; Bc[g] = b * gscale[g];
  }

  // ---- W_hh B-fragments (prescaled, hi+lo exact, constant across steps) ----
  short8 Bhi[4][2], Blo[4][2];
#pragma unroll
  for (int g = 0; g < 4; ++g) {
#pragma unroll
    for (int kk = 0; kk < 2; ++kk) {
      const float4* wp = (const float4*)(W_hh + (size_t)(g * 64 + dcol) * D
                                         + kk * 32 + quad * 8);
      float wv[8];
      float4 w0 = wp[0], w1 = wp[1];
      wv[0]=w0.x; wv[1]=w0.y; wv[2]=w0.z; wv[3]=w0.w;
      wv[4]=w1.x; wv[5]=w1.y; wv[6]=w1.z; wv[7]=w1.w;
      short8 hi8, lo8;
#pragma unroll
      for (int j = 0; j < 8; ++j) {
        float v = wv[j] * gscale[g];
        unsigned short h = f2bf_rtne(v);
        hi8[j] = (short)h;
        lo8[j] = (short)f2bf_rtne(v - bf2f(h));
      }
      Bhi[g][kk] = hi8; Blo[g][kk] = lo8;
    }
  }

  float creg[2] = {0.f, 0.f};    // cell state for real rows quad*2 + {0,1}
  float hreg[2] = {0.f, 0.f};
  __syncthreads();

  int p = 0;
  for (int t4 = 0; t4 < L; t4 += 4) {
    // 4 steps' worth of x per real row (quad*2+r) in one b128 each
    float4 xq[2];
#pragma unroll
    for (int r = 0; r < 2; ++r)
      xq[r] = *(const float4*)&xs[(quad * 2 + r) * XSS + t4];
#pragma unroll
    for (int u = 0; u < 4; ++u) {
      // A-fragment of h(t-1): m=c16 (tile-rows; ==2,3 mod 4 are zero)
      short8 ahi[2];
#pragma unroll
      for (int kk = 0; kk < 2; ++kk)
        ahi[kk] = *(const short8*)&hb[p][c16 * HBS + kk * 32 + quad * 8];
      float xv[2] = {xq[0][u], xq[1][u]};
      floatx4 acc[4];
#pragma unroll
      for (int g = 0; g < 4; ++g)
        acc[g] = (floatx4){fmaf(An[g], xv[0], Bc[g]), fmaf(An[g], xv[1], Bc[g]),
                           0.0f, 0.0f};
#pragma unroll
      for (int kk = 0; kk < 2; ++kk) {
#pragma unroll
        for (int g = 0; g < 4; ++g) {
          acc[g] = __builtin_amdgcn_mfma_f32_16x16x32_bf16(ahi[kk], Bhi[g][kk], acc[g], 0, 0, 0);
          acc[g] = __builtin_amdgcn_mfma_f32_16x16x32_bf16(ahi[kk], Blo[g][kk], acc[g], 0, 0, 0);
        }
      }
      // merged elementwise: 2 valid cells/lane (tile-rows quad*4+{0,1})
#pragma unroll
      for (int r = 0; r < 2; ++r) {
        float Ei = ex2(acc[0][r]);   // e^{-i}
        float Ef = ex2(acc[1][r]);   // e^{-f}
        float Eg = ex2(acc[2][r]);   // e^{-2g}
        float Eo = ex2(acc[3][r]);   // e^{-o}
        float pf = 1.0f + Ef, pi = 1.0f + Ei, pg = 1.0f + Eg;
        float mg = 1.0f - Eg;
        float pig = pi * pg;
        float num = fmaf(creg[r], pig, mg * pf);
        float c2  = num * fast_rcp(pf * pig);
        float Ec  = ex2(-2.0f * LOG2E * c2);
        float po = 1.0f + Eo, pc = 1.0f + Ec, mc = 1.0f - Ec;
        float h2 = mc * fast_rcp(po * pc);
        creg[r] = c2;
        hreg[r] = h2;
        int trow = quad * 4 + r;     // tile-row
        hb[p ^ 1][trow * HBS + dcol] = (short)f2bf_rtne(h2);
      }
      __syncthreads();
      p ^= 1;
    }
  }

  // ---- tail: h_hat = h@W_aout.T+b ; f = h_hat@W_fh.T+b ; partial sums ----
  // x tile dead: xs[row][0..63] = h fp32, xs[row][64..127] = h_hat (real rows)
#pragma unroll
  for (int r = 0; r < 2; ++r) xs[(quad * 2 + r) * XSS + dcol] = hreg[r];
  __syncthreads();

  float hhat[2];
#pragma unroll
  for (int r = 0; r < 2; ++r) {
    float a = b_aout[dcol];
    const float4* wa = (const float4*)(W_aout + (size_t)dcol * D);
    const float* hp = &xs[(quad * 2 + r) * XSS];
#pragma unroll
    for (int e4 = 0; e4 < 16; ++e4) {
      float4 wv = wa[e4];
      a = fmaf(wv.x, hp[e4*4+0], a); a = fmaf(wv.y, hp[e4*4+1], a);
      a = fmaf(wv.z, hp[e4*4+2], a); a = fmaf(wv.w, hp[e4*4+3], a);
    }
    hhat[r] = a;
  }
  __syncthreads();
#pragma unroll
  for (int r = 0; r < 2; ++r) xs[(quad * 2 + r) * XSS + 64 + dcol] = hhat[r];
  __syncthreads();

  float pfc = 0.0f, phs = 0.0f;
#pragma unroll
  for (int r = 0; r < 2; ++r) {
    float f = b_fh[dcol];
    const float4* wf = (const float4*)(W_fh + (size_t)dcol * D);
    const float* hp = &xs[(quad * 2 + r) * XSS + 64];
#pragma unroll
    for (int e4 = 0; e4 < 16; ++e4) {
      float4 wv = wf[e4];
      f = fmaf(wv.x, hp[e4*4+0], f); f = fmaf(wv.y, hp[e4*4+1], f);
      f = fmaf(wv.z, hp[e4*4+2], f); f = fmaf(wv.w, hp[e4*4+3], f);
    }
    pfc = fmaf(sig_plain(f), creg[r], pfc);
    phs += hhat[r];
  }
  // rows are spread across quads (same dcol per c16 lane): reduce over quads
  pfc += __shfl_xor(pfc, 16); pfc += __shfl_xor(pfc, 32);
  phs += __shfl_xor(phs, 16); phs += __shfl_xor(phs, 32);
  if (quad == 0) {
    atomicAdd(acc_out + dcol, pfc);
    atomicAdd(acc_out + D + dcol, phs);
  }

  // ---- last-block finish ----
  __threadfence();
  if (tid == 0) {
    unsigned int prev = __hip_atomic_fetch_add((unsigned int*)(acc_out + 2 * D), 1u,
                                               __ATOMIC_ACQ_REL, __HIP_MEMORY_SCOPE_AGENT);
    is_last = (prev == NBLK - 1) ? 1 : 0;
  }
  __syncthreads();
  if (!is_last) return;
  __threadfence();
  if (tid < 2 * D)
    sacc[tid] = __hip_atomic_load(acc_out + tid, __ATOMIC_RELAXED, __HIP_MEMORY_SCOPE_AGENT);
  __syncthreads();
  if (tid < D) {
    const int d = tid;
    float vi = b_iouh[d], vo = b_iouh[D + d], vu = b_iouh[2 * D + d];
    for (int e = 0; e < D; ++e) {
      float hs = sacc[D + e];
      vi = fmaf(W_iouh[(size_t)d * D + e],           hs, vi);
      vo = fmaf(W_iouh[(size_t)(D + d) * D + e],     hs, vo);
      vu = fmaf(W_iouh[(size_t)(2 * D + d) * D + e], hs, vu);
    }
    float c_obj = sig_plain(vi) * tanh2(-2.0f * LOG2E * vu) + sacc[d];
    float h_obj = sig_plain(vo) * tanh2(-2.0f * LOG2E * c_obj);
    hobj[d] = h_obj;
    out[D + d] = c_obj;
  }
  __syncthreads();
  if (tid < D) {
    const int d = tid;
    float hh = b_oout[d];
    for (int e = 0; e < D; ++e) hh = fmaf(W_oout[(size_t)d * D + e], hobj[e], hh);
    out[d] = hh;
  }
}

extern "C" void kernel_launch(void* const* d_in, const int* in_sizes, int n_in,
                              void* d_out, int out_size, void* d_ws, size_t ws_size,
                              hipStream_t stream) {
  const float* x      = (const float*)d_in[0];
  const float* W_num  = (const float*)d_in[1];
  const float* b_num  = (const float*)d_in[2];
  const float* W_ih   = (const float*)d_in[3];
  const float* W_hh   = (const float*)d_in[4];
  const float* b_ih   = (const float*)d_in[5];
  const float* b_hh   = (const float*)d_in[6];
  const float* W_aout = (const float*)d_in[7];
  const float* b_aout = (const float*)d_in[8];
  const float* W_fh   = (const float*)d_in[9];
  const float* b_fh   = (const float*)d_in[10];
  const float* W_iouh = (const float*)d_in[11];
  const float* b_iouh = (const float*)d_in[12];
  const float* W_oout = (const float*)d_in[13];
  const float* b_oout = (const float*)d_in[14];
  float* acc = (float*)d_ws;
  float* out = (float*)d_out;

  hipMemsetAsync(d_ws, 0, (2 * D + 1) * sizeof(float), stream);
  lstm_main<<<NBLK, NT, 0, stream>>>(x, W_num, b_num, W_ih, W_hh, b_ih, b_hh,
                                     W_aout, b_aout, W_fh, b_fh,
                                     W_iouh, b_iouh, W_oout, b_oout, acc, out);
}

// Round 10
// 207.361 us; speedup vs baseline: 1.3144x; 1.3068x over previous
//
#include <hip/hip_runtime.h>
#include <cstddef>

#define D   64
#define L   128
#define NT  256            // 4 waves per block
#define ROWS 16            // one M=16 MFMA tile per block
#define XSS 132            // padded floats (mult of 4 keeps float4 alignment)
#define HBS 72             // shorts
#define NBLK 512           // 8192 / 16
#define LOG2E 1.4426950408889634f

typedef __attribute__((ext_vector_type(8))) short short8;
typedef __attribute__((ext_vector_type(4))) float floatx4;

__device__ __forceinline__ float fast_rcp(float x) {
#if defined(__has_builtin)
#if __has_builtin(__builtin_amdgcn_rcpf)
  return __builtin_amdgcn_rcpf(x);
#else
  return 1.0f / x;
#endif
#else
  return 1.0f / x;
#endif
}
__device__ __forceinline__ float ex2(float x) {
#if defined(__has_builtin)
#if __has_builtin(__builtin_amdgcn_exp2f)
  return __builtin_amdgcn_exp2f(x);
#else
  return __builtin_exp2f(x);
#endif
#else
  return __builtin_exp2f(x);
#endif
}
__device__ __forceinline__ float sig_plain(float x) {
  return fast_rcp(1.0f + ex2(-LOG2E * x));
}
__device__ __forceinline__ float tanh2(float G) {   // tanh(x), G = -2log2e*x
  return fmaf(2.0f, fast_rcp(1.0f + ex2(G)), -1.0f);
}
__device__ __forceinline__ unsigned short f2bf_rtne(float f) {
  unsigned int u = __float_as_uint(f);
  u += 0x7fffu + ((u >> 16) & 1u);
  return (unsigned short)(u >> 16);
}
__device__ __forceinline__ float bf2f(unsigned short s) {
  return __uint_as_float(((unsigned int)s) << 16);
}

// Persistent 16-row LSTM scan (R7 structure — empirical winner: 512 blocks x
// 4 waves = 2 blocks/CU, 2 waves/SIMD; wave w owns d in [16w,16w+16) for all
// 4 gates -> gates register-resident, ONE barrier/step).
// R10 change: SINGLE-bf16 W_hh (Blo dropped) -> 8 MFMAs/wave/step. Model:
// the matrix pipe is CU-shared at ~4.85 cyc/MFMA (m06 µbench per-CU rate;
// confirmed by R3->R7 step-time deltas), so halving MFMA count removes
// ~310 cyc/step of serialized CU matrix-pipe time.
// A = rtne-bf16(h) (random rounding, averages over 8192 rows); W rounding
// adds a comparable random term through the 64-d contraction.
// Gates prescaled by -log2e (-2log2e for g): 5 exp2 + 2 rcp per cell.
__global__ __launch_bounds__(NT, 2)
void lstm_main(const float* __restrict__ x,
               const float* __restrict__ W_num,
               const float* __restrict__ b_num,
               const float* __restrict__ W_ih,
               const float* __restrict__ W_hh,
               const float* __restrict__ b_ih,
               const float* __restrict__ b_hh,
               const float* __restrict__ W_aout,
               const float* __restrict__ b_aout,
               const float* __restrict__ W_fh,
               const float* __restrict__ b_fh,
               const float* __restrict__ W_iouh,
               const float* __restrict__ b_iouh,
               const float* __restrict__ W_oout,
               const float* __restrict__ b_oout,
               float* __restrict__ acc_out,   // [0..63]=fc, [64..127]=hs, [128]=ticket
               float* __restrict__ out)
{
  __shared__ __align__(16) float xs[ROWS * XSS];       // 8.25 KB (x; later h/h_hat)
  __shared__ __align__(16) short hb[2][ROWS * HBS];    // 4.5 KB double-buffered bf16 h
  __shared__ float sacc[2 * D];
  __shared__ float hobj[D];
  __shared__ int   is_last;

  const int tid  = threadIdx.x;
  const int w    = tid >> 6;
  const int lane = tid & 63;
  const int quad = lane >> 4;
  const int c16  = lane & 15;
  const int k0   = blockIdx.x * ROWS;
  const int dcol = w * 16 + c16;

  // ---- stage x tile (16 rows x 128), coalesced ----
  for (int i = tid; i < ROWS * (L / 4); i += NT) {
    int r = i >> 5, c4 = i & 31;
    float4 v = ((const float4*)(x + (size_t)(k0 + r) * L))[c4];
    float* dst = &xs[r * XSS + c4 * 4];
    dst[0] = v.x; dst[1] = v.y; dst[2] = v.z; dst[3] = v.w;
  }
  for (int i = tid; i < ROWS * HBS; i += NT) hb[0][i] = 0;

  // per-gate exp2 prescale (g-gate feeds tanh -> -2log2e)
  const float gscale[4] = {-LOG2E, -LOG2E, -2.0f * LOG2E, -LOG2E};

  // ---- rank-1 x-projection constants (prescaled), float4 loads ----
  float An[4], Bc[4];
#pragma unroll
  for (int g = 0; g < 4; ++g) {
    int j = g * 64 + dcol;
    const float4* wr = (const float4*)(W_ih + (size_t)j * (2 * D));
    float a = 0.0f, b = b_ih[j] + b_hh[j];
#pragma unroll
    for (int e4 = 0; e4 < 16; ++e4) {
      float4 wv = wr[e4];
      float4 wn = ((const float4*)W_num)[e4];
      float4 bn = ((const float4*)b_num)[e4];
      a = fmaf(wn.x, wv.x, a); a = fmaf(wn.y, wv.y, a);
      a = fmaf(wn.z, wv.z, a); a = fmaf(wn.w, wv.w, a);
      b = fmaf(bn.x, wv.x, b); b = fmaf(bn.y, wv.y, b);
      b = fmaf(bn.z, wv.z, b); b = fmaf(bn.w, wv.w, b);
    }
    An[g] = a * gscale[g]; Bc[g] = b * gscale[g];
  }

  // ---- W_hh B-fragments (prescaled, single RTNE bf16, constant) ----
  short8 Bf[4][2];
#pragma unroll
  for (int g = 0; g < 4; ++g) {
#pragma unroll
    for (int kk = 0; kk < 2; ++kk) {
      const float4* wp = (const float4*)(W_hh + (size_t)(g * 64 + dcol) * D
                                         + kk * 32 + quad * 8);
      float wv[8];
      float4 w0 = wp[0], w1 = wp[1];
      wv[0]=w0.x; wv[1]=w0.y; wv[2]=w0.z; wv[3]=w0.w;
      wv[4]=w1.x; wv[5]=w1.y; wv[6]=w1.z; wv[7]=w1.w;
      short8 hi8;
#pragma unroll
      for (int j = 0; j < 8; ++j)
        hi8[j] = (short)f2bf_rtne(wv[j] * gscale[g]);
      Bf[g][kk] = hi8;
    }
  }

  float creg[4] = {0.f, 0.f, 0.f, 0.f};
  float hreg[4] = {0.f, 0.f, 0.f, 0.f};
  __syncthreads();

  int p = 0;
  for (int t4 = 0; t4 < L; t4 += 4) {
    // 4 steps' worth of x per row in one b128 each
    float4 xq[4];
#pragma unroll
    for (int r = 0; r < 4; ++r)
      xq[r] = *(const float4*)&xs[(quad * 4 + r) * XSS + t4];
#pragma unroll
    for (int u = 0; u < 4; ++u) {
      // A-fragment of h(t-1): m=c16, k=kk*32+quad*8+j (single rtne-bf16)
      short8 ahi[2];
#pragma unroll
      for (int kk = 0; kk < 2; ++kk)
        ahi[kk] = *(const short8*)&hb[p][c16 * HBS + kk * 32 + quad * 8];
      float xv[4] = {xq[0][u], xq[1][u], xq[2][u], xq[3][u]};
      floatx4 acc[4];
#pragma unroll
      for (int g = 0; g < 4; ++g)
        acc[g] = (floatx4){fmaf(An[g], xv[0], Bc[g]), fmaf(An[g], xv[1], Bc[g]),
                           fmaf(An[g], xv[2], Bc[g]), fmaf(An[g], xv[3], Bc[g])};
#pragma unroll
      for (int kk = 0; kk < 2; ++kk) {
#pragma unroll
        for (int g = 0; g < 4; ++g)
          acc[g] = __builtin_amdgcn_mfma_f32_16x16x32_bf16(ahi[kk], Bf[g][kk], acc[g], 0, 0, 0);
      }
      // merged elementwise: 5 exp2 + 2 rcp per cell, in registers
#pragma unroll
      for (int r = 0; r < 4; ++r) {
        float Ei = ex2(acc[0][r]);   // e^{-i}
        float Ef = ex2(acc[1][r]);   // e^{-f}
        float Eg = ex2(acc[2][r]);   // e^{-2g}
        float Eo = ex2(acc[3][r]);   // e^{-o}
        float pf = 1.0f + Ef, pi = 1.0f + Ei, pg = 1.0f + Eg;
        float mg = 1.0f - Eg;
        float pig = pi * pg;
        float num = fmaf(creg[r], pig, mg * pf);
        float c2  = num * fast_rcp(pf * pig);
        float Ec  = ex2(-2.0f * LOG2E * c2);
        float po = 1.0f + Eo, pc = 1.0f + Ec, mc = 1.0f - Ec;
        float h2 = mc * fast_rcp(po * pc);
        creg[r] = c2;
        hreg[r] = h2;
        int row = quad * 4 + r;
        hb[p ^ 1][row * HBS + dcol] = (short)f2bf_rtne(h2);
      }
      __syncthreads();
      p ^= 1;
    }
  }

  // ---- tail: h_hat = h@W_aout.T+b ; f = h_hat@W_fh.T+b ; partial sums ----
  // x tile dead: xs[row][0..63] = h fp32, xs[row][64..127] = h_hat
#pragma unroll
  for (int r = 0; r < 4; ++r) xs[(quad * 4 + r) * XSS + dcol] = hreg[r];
  __syncthreads();

  float hhat[4];
#pragma unroll
  for (int r = 0; r < 4; ++r) {
    float a = b_aout[dcol];
    const float4* wa = (const float4*)(W_aout + (size_t)dcol * D);
    const float* hp = &xs[(quad * 4 + r) * XSS];
#pragma unroll
    for (int e4 = 0; e4 < 16; ++e4) {
      float4 wv = wa[e4];
      a = fmaf(wv.x, hp[e4*4+0], a); a = fmaf(wv.y, hp[e4*4+1], a);
      a = fmaf(wv.z, hp[e4*4+2], a); a = fmaf(wv.w, hp[e4*4+3], a);
    }
    hhat[r] = a;
  }
  __syncthreads();
#pragma unroll
  for (int r = 0; r < 4; ++r) xs[(quad * 4 + r) * XSS + 64 + dcol] = hhat[r];
  __syncthreads();

  float pfc = 0.0f, phs = 0.0f;
#pragma unroll
  for (int r = 0; r < 4; ++r) {
    float f = b_fh[dcol];
    const float4* wf = (const float4*)(W_fh + (size_t)dcol * D);
    const float* hp = &xs[(quad * 4 + r) * XSS + 64];
#pragma unroll
    for (int e4 = 0; e4 < 16; ++e4) {
      float4 wv = wf[e4];
      f = fmaf(wv.x, hp[e4*4+0], f); f = fmaf(wv.y, hp[e4*4+1], f);
      f = fmaf(wv.z, hp[e4*4+2], f); f = fmaf(wv.w, hp[e4*4+3], f);
    }
    pfc = fmaf(sig_plain(f), creg[r], pfc);
    phs += hhat[r];
  }
  pfc += __shfl_xor(pfc, 16); pfc += __shfl_xor(pfc, 32);
  phs += __shfl_xor(phs, 16); phs += __shfl_xor(phs, 32);
  if (quad == 0) {
    atomicAdd(acc_out + dcol, pfc);
    atomicAdd(acc_out + D + dcol, phs);
  }

  // ---- last-block finish ----
  __threadfence();
  if (tid == 0) {
    unsigned int prev = __hip_atomic_fetch_add((unsigned int*)(acc_out + 2 * D), 1u,
                                               __ATOMIC_ACQ_REL, __HIP_MEMORY_SCOPE_AGENT);
    is_last = (prev == NBLK - 1) ? 1 : 0;
  }
  __syncthreads();
  if (!is_last) return;
  __threadfence();
  if (tid < 2 * D)
    sacc[tid] = __hip_atomic_load(acc_out + tid, __ATOMIC_RELAXED, __HIP_MEMORY_SCOPE_AGENT);
  __syncthreads();
  if (tid < D) {
    const int d = tid;
    float vi = b_iouh[d], vo = b_iouh[D + d], vu = b_iouh[2 * D + d];
    for (int e = 0; e < D; ++e) {
      float hs = sacc[D + e];
      vi = fmaf(W_iouh[(size_t)d * D + e],           hs, vi);
      vo = fmaf(W_iouh[(size_t)(D + d) * D + e],     hs, vo);
      vu = fmaf(W_iouh[(size_t)(2 * D + d) * D + e], hs, vu);
    }
    float c_obj = sig_plain(vi) * tanh2(-2.0f * LOG2E * vu) + sacc[d];
    float h_obj = sig_plain(vo) * tanh2(-2.0f * LOG2E * c_obj);
    hobj[d] = h_obj;
    out[D + d] = c_obj;
  }
  __syncthreads();
  if (tid < D) {
    const int d = tid;
    float hh = b_oout[d];
    for (int e = 0; e < D; ++e) hh = fmaf(W_oout[(size_t)d * D + e], hobj[e], hh);
    out[d] = hh;
  }
}

extern "C" void kernel_launch(void* const* d_in, const int* in_sizes, int n_in,
                              void* d_out, int out_size, void* d_ws, size_t ws_size,
                              hipStream_t stream) {
  const float* x      = (const float*)d_in[0];
  const float* W_num  = (const float*)d_in[1];
  const float* b_num  = (const float*)d_in[2];
  const float* W_ih   = (const float*)d_in[3];
  const float* W_hh   = (const float*)d_in[4];
  const float* b_ih   = (const float*)d_in[5];
  const float* b_hh   = (const float*)d_in[6];
  const float* W_aout = (const float*)d_in[7];
  const float* b_aout = (const float*)d_in[8];
  const float* W_fh   = (const float*)d_in[9];
  const float* b_fh   = (const float*)d_in[10];
  const float* W_iouh = (const float*)d_in[11];
  const float* b_iouh = (const float*)d_in[12];
  const float* W_oout = (const float*)d_in[13];
  const float* b_oout = (const float*)d_in[14];
  float* acc = (float*)d_ws;
  float* out = (float*)d_out;

  hipMemsetAsync(d_ws, 0, (2 * D + 1) * sizeof(float), stream);
  lstm_main<<<NBLK, NT, 0, stream>>>(x, W_num, b_num, W_ih, W_hh, b_ih, b_hh,
                                     W_aout, b_aout, W_fh, b_fh,
                                     W_iouh, b_iouh, W_oout, b_oout, acc, out);
}

// Round 11
// 200.507 us; speedup vs baseline: 1.3593x; 1.0342x over previous
//
#include <hip/hip_runtime.h>
#include <cstddef>

#define D   64
#define L   128
#define NT  256            // 4 waves per block
#define ROWS 16            // one M=16 MFMA tile per block
#define XSS 132            // padded floats (mult of 4 keeps float4 alignment)
#define HBS 72             // shorts
#define NBLK 512           // 8192 / 16
#define LOG2E 1.4426950408889634f

typedef __attribute__((ext_vector_type(8))) short short8;
typedef __attribute__((ext_vector_type(4))) float floatx4;
typedef __attribute__((ext_vector_type(2))) float f2;

__device__ __forceinline__ float fast_rcp(float x) {
#if defined(__has_builtin)
#if __has_builtin(__builtin_amdgcn_rcpf)
  return __builtin_amdgcn_rcpf(x);
#else
  return 1.0f / x;
#endif
#else
  return 1.0f / x;
#endif
}
__device__ __forceinline__ float ex2(float x) {
#if defined(__has_builtin)
#if __has_builtin(__builtin_amdgcn_exp2f)
  return __builtin_amdgcn_exp2f(x);
#else
  return __builtin_exp2f(x);
#endif
#else
  return __builtin_exp2f(x);
#endif
}
__device__ __forceinline__ f2 ex2_2(f2 v) { return (f2){ex2(v.x), ex2(v.y)}; }
__device__ __forceinline__ f2 rcp_2(f2 v) { return (f2){fast_rcp(v.x), fast_rcp(v.y)}; }
__device__ __forceinline__ float sig_plain(float x) {
  return fast_rcp(1.0f + ex2(-LOG2E * x));
}
__device__ __forceinline__ float tanh2(float G) {   // tanh(x), G = -2log2e*x
  return fmaf(2.0f, fast_rcp(1.0f + ex2(G)), -1.0f);
}
__device__ __forceinline__ unsigned short f2bf_rtne(float f) {
  unsigned int u = __float_as_uint(f);
  u += 0x7fffu + ((u >> 16) & 1u);
  return (unsigned short)(u >> 16);
}
__device__ __forceinline__ float bf2f(unsigned short s) {
  return __uint_as_float(((unsigned int)s) << 16);
}

// Persistent 16-row LSTM scan (R7/R10 structure — the empirical winner:
// 512 blocks x 4 waves = 2 blocks/CU, 2 waves/SIMD; wave w owns d in
// [16w,16w+16) for all 4 gates -> gates register-resident, ONE barrier/step;
// single-bf16 W_hh = 8 MFMAs/wave/step, ~4.85cyc/MFMA CU-shared pipe model
// confirmed by R10's -300cyc/step).
// R11 change: elementwise + C-init arithmetic in packed fp32 (float2 ->
// v_pk_fma_f32 / v_pk_add_f32 / v_pk_mul_f32) over cell pairs; only the 7
// transcendentals/cell (5 exp2 + 2 rcp) stay scalar. Same math, same RTNE
// bf16 pack -> absmax must stay identical (8.0).
__global__ __launch_bounds__(NT, 2)
void lstm_main(const float* __restrict__ x,
               const float* __restrict__ W_num,
               const float* __restrict__ b_num,
               const float* __restrict__ W_ih,
               const float* __restrict__ W_hh,
               const float* __restrict__ b_ih,
               const float* __restrict__ b_hh,
               const float* __restrict__ W_aout,
               const float* __restrict__ b_aout,
               const float* __restrict__ W_fh,
               const float* __restrict__ b_fh,
               const float* __restrict__ W_iouh,
               const float* __restrict__ b_iouh,
               const float* __restrict__ W_oout,
               const float* __restrict__ b_oout,
               float* __restrict__ acc_out,   // [0..63]=fc, [64..127]=hs, [128]=ticket
               float* __restrict__ out)
{
  __shared__ __align__(16) float xs[ROWS * XSS];       // 8.25 KB (x; later h/h_hat)
  __shared__ __align__(16) short hb[2][ROWS * HBS];    // 4.5 KB double-buffered bf16 h
  __shared__ float sacc[2 * D];
  __shared__ float hobj[D];
  __shared__ int   is_last;

  const int tid  = threadIdx.x;
  const int w    = tid >> 6;
  const int lane = tid & 63;
  const int quad = lane >> 4;
  const int c16  = lane & 15;
  const int k0   = blockIdx.x * ROWS;
  const int dcol = w * 16 + c16;

  // ---- stage x tile (16 rows x 128), coalesced ----
  for (int i = tid; i < ROWS * (L / 4); i += NT) {
    int r = i >> 5, c4 = i & 31;
    float4 v = ((const float4*)(x + (size_t)(k0 + r) * L))[c4];
    float* dst = &xs[r * XSS + c4 * 4];
    dst[0] = v.x; dst[1] = v.y; dst[2] = v.z; dst[3] = v.w;
  }
  for (int i = tid; i < ROWS * HBS; i += NT) hb[0][i] = 0;

  // per-gate exp2 prescale (g-gate feeds tanh -> -2log2e)
  const float gscale[4] = {-LOG2E, -LOG2E, -2.0f * LOG2E, -LOG2E};

  // ---- rank-1 x-projection constants (prescaled), float4 loads ----
  float An[4], Bc[4];
#pragma unroll
  for (int g = 0; g < 4; ++g) {
    int j = g * 64 + dcol;
    const float4* wr = (const float4*)(W_ih + (size_t)j * (2 * D));
    float a = 0.0f, b = b_ih[j] + b_hh[j];
#pragma unroll
    for (int e4 = 0; e4 < 16; ++e4) {
      float4 wv = wr[e4];
      float4 wn = ((const float4*)W_num)[e4];
      float4 bn = ((const float4*)b_num)[e4];
      a = fmaf(wn.x, wv.x, a); a = fmaf(wn.y, wv.y, a);
      a = fmaf(wn.z, wv.z, a); a = fmaf(wn.w, wv.w, a);
      b = fmaf(bn.x, wv.x, b); b = fmaf(bn.y, wv.y, b);
      b = fmaf(bn.z, wv.z, b); b = fmaf(bn.w, wv.w, b);
    }
    An[g] = a * gscale[g]; Bc[g] = b * gscale[g];
  }

  // ---- W_hh B-fragments (prescaled, single RTNE bf16, constant) ----
  short8 Bf[4][2];
#pragma unroll
  for (int g = 0; g < 4; ++g) {
#pragma unroll
    for (int kk = 0; kk < 2; ++kk) {
      const float4* wp = (const float4*)(W_hh + (size_t)(g * 64 + dcol) * D
                                         + kk * 32 + quad * 8);
      float wv[8];
      float4 w0 = wp[0], w1 = wp[1];
      wv[0]=w0.x; wv[1]=w0.y; wv[2]=w0.z; wv[3]=w0.w;
      wv[4]=w1.x; wv[5]=w1.y; wv[6]=w1.z; wv[7]=w1.w;
      short8 hi8;
#pragma unroll
      for (int j = 0; j < 8; ++j)
        hi8[j] = (short)f2bf_rtne(wv[j] * gscale[g]);
      Bf[g][kk] = hi8;
    }
  }

  const f2 one2  = {1.0f, 1.0f};
  const f2 m2l2  = {-2.0f * LOG2E, -2.0f * LOG2E};
  f2 creg2[2] = {{0.f, 0.f}, {0.f, 0.f}};   // cell pairs (r0,r1),(r2,r3)
  f2 hreg2[2] = {{0.f, 0.f}, {0.f, 0.f}};
  __syncthreads();

  int p = 0;
  for (int t4 = 0; t4 < L; t4 += 4) {
    // 4 steps' worth of x per row in one b128 each
    float4 xq[4];
#pragma unroll
    for (int r = 0; r < 4; ++r)
      xq[r] = *(const float4*)&xs[(quad * 4 + r) * XSS + t4];
#pragma unroll
    for (int u = 0; u < 4; ++u) {
      // A-fragment of h(t-1): m=c16, k=kk*32+quad*8+j (single rtne-bf16)
      short8 ahi[2];
#pragma unroll
      for (int kk = 0; kk < 2; ++kk)
        ahi[kk] = *(const short8*)&hb[p][c16 * HBS + kk * 32 + quad * 8];
      f2 xv01 = {xq[0][u], xq[1][u]};
      f2 xv23 = {xq[2][u], xq[3][u]};
      floatx4 acc[4];
#pragma unroll
      for (int g = 0; g < 4; ++g) {
        f2 A2 = {An[g], An[g]}, B2 = {Bc[g], Bc[g]};
        f2 i01 = A2 * xv01 + B2;        // v_pk_fma_f32
        f2 i23 = A2 * xv23 + B2;
        acc[g] = (floatx4){i01.x, i01.y, i23.x, i23.y};
      }
#pragma unroll
      for (int kk = 0; kk < 2; ++kk) {
#pragma unroll
        for (int g = 0; g < 4; ++g)
          acc[g] = __builtin_amdgcn_mfma_f32_16x16x32_bf16(ahi[kk], Bf[g][kk], acc[g], 0, 0, 0);
      }
      // merged elementwise on cell PAIRS: packed arith, scalar trans
#pragma unroll
      for (int h = 0; h < 2; ++h) {
        f2 Gi = {acc[0][2*h], acc[0][2*h+1]};
        f2 Gf = {acc[1][2*h], acc[1][2*h+1]};
        f2 Gg = {acc[2][2*h], acc[2][2*h+1]};
        f2 Go = {acc[3][2*h], acc[3][2*h+1]};
        f2 Ei = ex2_2(Gi), Ef = ex2_2(Gf), Eg = ex2_2(Gg), Eo = ex2_2(Go);
        f2 pf = Ef + one2, pi = Ei + one2, pg = Eg + one2, mg = one2 - Eg;
        f2 pig = pi * pg;
        f2 num = creg2[h] * pig + mg * pf;
        f2 c2  = num * rcp_2(pf * pig);
        creg2[h] = c2;
        f2 Ec = ex2_2(c2 * m2l2);
        f2 po = Eo + one2, pc = Ec + one2, mc = one2 - Ec;
        f2 h2 = mc * rcp_2(po * pc);
        hreg2[h] = h2;
        int row0 = quad * 4 + 2 * h;
        hb[p ^ 1][row0 * HBS + dcol]       = (short)f2bf_rtne(h2.x);
        hb[p ^ 1][(row0 + 1) * HBS + dcol] = (short)f2bf_rtne(h2.y);
      }
      __syncthreads();
      p ^= 1;
    }
  }

  // unpack pair registers for the tail
  float creg[4] = {creg2[0].x, creg2[0].y, creg2[1].x, creg2[1].y};
  float hreg[4] = {hreg2[0].x, hreg2[0].y, hreg2[1].x, hreg2[1].y};

  // ---- tail: h_hat = h@W_aout.T+b ; f = h_hat@W_fh.T+b ; partial sums ----
  // x tile dead: xs[row][0..63] = h fp32, xs[row][64..127] = h_hat
#pragma unroll
  for (int r = 0; r < 4; ++r) xs[(quad * 4 + r) * XSS + dcol] = hreg[r];
  __syncthreads();

  float hhat[4];
#pragma unroll
  for (int r = 0; r < 4; ++r) {
    float a = b_aout[dcol];
    const float4* wa = (const float4*)(W_aout + (size_t)dcol * D);
    const float* hp = &xs[(quad * 4 + r) * XSS];
#pragma unroll
    for (int e4 = 0; e4 < 16; ++e4) {
      float4 wv = wa[e4];
      a = fmaf(wv.x, hp[e4*4+0], a); a = fmaf(wv.y, hp[e4*4+1], a);
      a = fmaf(wv.z, hp[e4*4+2], a); a = fmaf(wv.w, hp[e4*4+3], a);
    }
    hhat[r] = a;
  }
  __syncthreads();
#pragma unroll
  for (int r = 0; r < 4; ++r) xs[(quad * 4 + r) * XSS + 64 + dcol] = hhat[r];
  __syncthreads();

  float pfc = 0.0f, phs = 0.0f;
#pragma unroll
  for (int r = 0; r < 4; ++r) {
    float f = b_fh[dcol];
    const float4* wf = (const float4*)(W_fh + (size_t)dcol * D);
    const float* hp = &xs[(quad * 4 + r) * XSS + 64];
#pragma unroll
    for (int e4 = 0; e4 < 16; ++e4) {
      float4 wv = wf[e4];
      f = fmaf(wv.x, hp[e4*4+0], f); f = fmaf(wv.y, hp[e4*4+1], f);
      f = fmaf(wv.z, hp[e4*4+2], f); f = fmaf(wv.w, hp[e4*4+3], f);
    }
    pfc = fmaf(sig_plain(f), creg[r], pfc);
    phs += hhat[r];
  }
  pfc += __shfl_xor(pfc, 16); pfc += __shfl_xor(pfc, 32);
  phs += __shfl_xor(phs, 16); phs += __shfl_xor(phs, 32);
  if (quad == 0) {
    atomicAdd(acc_out + dcol, pfc);
    atomicAdd(acc_out + D + dcol, phs);
  }

  // ---- last-block finish ----
  __threadfence();
  if (tid == 0) {
    unsigned int prev = __hip_atomic_fetch_add((unsigned int*)(acc_out + 2 * D), 1u,
                                               __ATOMIC_ACQ_REL, __HIP_MEMORY_SCOPE_AGENT);
    is_last = (prev == NBLK - 1) ? 1 : 0;
  }
  __syncthreads();
  if (!is_last) return;
  __threadfence();
  if (tid < 2 * D)
    sacc[tid] = __hip_atomic_load(acc_out + tid, __ATOMIC_RELAXED, __HIP_MEMORY_SCOPE_AGENT);
  __syncthreads();
  if (tid < D) {
    const int d = tid;
    float vi = b_iouh[d], vo = b_iouh[D + d], vu = b_iouh[2 * D + d];
    for (int e = 0; e < D; ++e) {
      float hs = sacc[D + e];
      vi = fmaf(W_iouh[(size_t)d * D + e],           hs, vi);
      vo = fmaf(W_iouh[(size_t)(D + d) * D + e],     hs, vo);
      vu = fmaf(W_iouh[(size_t)(2 * D + d) * D + e], hs, vu);
    }
    float c_obj = sig_plain(vi) * tanh2(-2.0f * LOG2E * vu) + sacc[d];
    float h_obj = sig_plain(vo) * tanh2(-2.0f * LOG2E * c_obj);
    hobj[d] = h_obj;
    out[D + d] = c_obj;
  }
  __syncthreads();
  if (tid < D) {
    const int d = tid;
    float hh = b_oout[d];
    for (int e = 0; e < D; ++e) hh = fmaf(W_oout[(size_t)d * D + e], hobj[e], hh);
    out[d] = hh;
  }
}

extern "C" void kernel_launch(void* const* d_in, const int* in_sizes, int n_in,
                              void* d_out, int out_size, void* d_ws, size_t ws_size,
                              hipStream_t stream) {
  const float* x      = (const float*)d_in[0];
  const float* W_num  = (const float*)d_in[1];
  const float* b_num  = (const float*)d_in[2];
  const float* W_ih   = (const float*)d_in[3];
  const float* W_hh   = (const float*)d_in[4];
  const float* b_ih   = (const float*)d_in[5];
  const float* b_hh   = (const float*)d_in[6];
  const float* W_aout = (const float*)d_in[7];
  const float* b_aout = (const float*)d_in[8];
  const float* W_fh   = (const float*)d_in[9];
  const float* b_fh   = (const float*)d_in[10];
  const float* W_iouh = (const float*)d_in[11];
  const float* b_iouh = (const float*)d_in[12];
  const float* W_oout = (const float*)d_in[13];
  const float* b_oout = (const float*)d_in[14];
  float* acc = (float*)d_ws;
  float* out = (float*)d_out;

  hipMemsetAsync(d_ws, 0, (2 * D + 1) * sizeof(float), stream);
  lstm_main<<<NBLK, NT, 0, stream>>>(x, W_num, b_num, W_ih, W_hh, b_ih, b_hh,
                                     W_aout, b_aout, W_fh, b_fh,
                                     W_iouh, b_iouh, W_oout, b_oout, acc, out);
}